// Round 2
// baseline (542.728 us; speedup 1.0000x reference)
//
#include <hip/hip_runtime.h>
#include <stdint.h>

typedef unsigned long long u64;
typedef int v2i __attribute__((ext_vector_type(2)));

#define K_MSG   1024
#define N_CODE  2048
#define NB      32768
#define KW      16        // 1024 bits / 64 = 16 u64 words per row/col
#define ROWS_TILE 256
#define COLS_TILE 128     // 2 columns per lane

// ---------------- pack b: [NB][K_MSG] int32 -> [NB][KW] u64 ----------------
__global__ void pack_b_kernel(const int* __restrict__ b, u64* __restrict__ bp,
                              int nwords) {
    const int lane  = threadIdx.x & 63;
    const int wave  = blockIdx.x * (blockDim.x >> 6) + (threadIdx.x >> 6);
    const int nwave = gridDim.x * (blockDim.x >> 6);
    for (int word = wave; word < nwords; word += nwave) {
        int v = b[(size_t)word * 64 + lane];
        u64 m = __ballot((v & 1) != 0);
        if (lane == 0) bp[word] = m;
    }
}

// ---------------- pack G: Gp[w][j], bit t = G[w*64+t][j] --------------------
__global__ void pack_g_kernel(const int* __restrict__ G, u64* __restrict__ gp) {
    const int lane = threadIdx.x & 63;
    const int wave = blockIdx.x * (blockDim.x >> 6) + (threadIdx.x >> 6); // 0..511
    const int w    = wave >> 5;   // 0..15
    const int jb   = wave & 31;   // 0..31
    const int j    = jb * 64 + lane;
    u64 word = 0;
#pragma unroll 16
    for (int t = 0; t < 64; ++t) {
        int v = G[(size_t)(w * 64 + t) * N_CODE + j];
        word |= (u64)(v & 1) << t;
    }
    gp[(size_t)w * N_CODE + j] = word;
}

// ---------------- main ------------------------------------------------------
// Block 256 thr = 4 waves. Lane owns columns j0, j0+1. Wave ty does rows
// r0+ty, +4, ... (64 iters). Software-pipelined row prefetch (a/b ping-pong).
#define TREE(buf, g, x) {                                        \
    u64 p0 = (buf[0]  & g[0])  ^ (buf[1]  & g[1]);               \
    u64 p1 = (buf[2]  & g[2])  ^ (buf[3]  & g[3]);               \
    u64 p2 = (buf[4]  & g[4])  ^ (buf[5]  & g[5]);               \
    u64 p3 = (buf[6]  & g[6])  ^ (buf[7]  & g[7]);               \
    u64 p4 = (buf[8]  & g[8])  ^ (buf[9]  & g[9]);               \
    u64 p5 = (buf[10] & g[10]) ^ (buf[11] & g[11]);              \
    u64 p6 = (buf[12] & g[12]) ^ (buf[13] & g[13]);              \
    u64 p7 = (buf[14] & g[14]) ^ (buf[15] & g[15]);              \
    x = ((p0 ^ p1) ^ (p2 ^ p3)) ^ ((p4 ^ p5) ^ (p6 ^ p7));       \
}

#define LOADROW(buf, s) {                                        \
    _Pragma("unroll")                                            \
    for (int w = 0; w < KW; ++w) buf[w] = rp[(size_t)(s) * 64 + w]; \
}

#define CSTORE(buf, s) {                                         \
    u64 x0, x1;                                                  \
    TREE(buf, g0, x0);                                           \
    TREE(buf, g1, x1);                                           \
    unsigned f0 = (unsigned)x0 ^ (unsigned)(x0 >> 32);           \
    unsigned f1 = (unsigned)x1 ^ (unsigned)(x1 >> 32);           \
    v2i r; r.x = __popc(f0) & 1; r.y = __popc(f1) & 1;           \
    __builtin_nontemporal_store(r, (v2i*)(op + (size_t)(s) * 4 * N_CODE)); \
}

__global__ __launch_bounds__(256, 3) void encode_main(const u64* __restrict__ bp,
                                                      const u64* __restrict__ gp,
                                                      int* __restrict__ out) {
    const int lane = threadIdx.x & 63;
    const int ty   = threadIdx.x >> 6;
    const int j0   = blockIdx.x * COLS_TILE + lane * 2;
    const int r0   = blockIdx.y * ROWS_TILE;

    u64 g0[KW], g1[KW];
#pragma unroll
    for (int w = 0; w < KW; ++w) {
        g0[w] = gp[(size_t)w * N_CODE + j0];
        g1[w] = gp[(size_t)w * N_CODE + j0 + 1];
    }

    const u64* __restrict__ rp = bp + ((size_t)(r0 + ty) << 4); // iter stride: 4 rows = 64 u64
    int* __restrict__ op = out + (size_t)(r0 + ty) * N_CODE + j0;

    u64 a[KW], b[KW];

    LOADROW(a, 0);
#pragma unroll 1
    for (int s = 0; s + 2 < 64; s += 2) {
        LOADROW(b, s + 1);
        CSTORE(a, s);
        LOADROW(a, s + 2);
        CSTORE(b, s + 1);
    }
    LOADROW(b, 63);
    CSTORE(a, 62);
    CSTORE(b, 63);
}

// ---------------- fallback (only if ws too small) ---------------------------
__global__ void encode_naive(const int* __restrict__ b, const int* __restrict__ G,
                             int* __restrict__ out) {
    size_t idx = (size_t)blockIdx.x * blockDim.x + threadIdx.x;
    size_t total = (size_t)NB * N_CODE;
    if (idx >= total) return;
    int i = (int)(idx / N_CODE);
    int j = (int)(idx % N_CODE);
    int acc = 0;
    for (int k = 0; k < K_MSG; ++k)
        acc ^= b[(size_t)i * K_MSG + k] & G[(size_t)k * N_CODE + j];
    out[idx] = acc & 1;
}

extern "C" void kernel_launch(void* const* d_in, const int* in_sizes, int n_in,
                              void* d_out, int out_size, void* d_ws, size_t ws_size,
                              hipStream_t stream) {
    const int* b = (const int*)d_in[0];
    const int* G = (const int*)d_in[1];
    int* out = (int*)d_out;

    const size_t bp_bytes = (size_t)NB * KW * sizeof(u64);      // 4 MiB
    const size_t gp_bytes = (size_t)N_CODE * KW * sizeof(u64);  // 256 KiB

    if (ws_size < bp_bytes + gp_bytes) {
        size_t total = (size_t)NB * N_CODE;
        encode_naive<<<(unsigned)((total + 255) / 256), 256, 0, stream>>>(b, G, out);
        return;
    }

    u64* bp = (u64*)d_ws;
    u64* gp = (u64*)((char*)d_ws + bp_bytes);

    pack_b_kernel<<<2048, 256, 0, stream>>>(b, bp, NB * KW);
    pack_g_kernel<<<128, 256, 0, stream>>>(G, gp);

    dim3 grid(N_CODE / COLS_TILE, NB / ROWS_TILE);  // 16 x 128
    encode_main<<<grid, 256, 0, stream>>>(bp, gp, out);
}

// Round 3
// 157.547 us; speedup vs baseline: 3.4449x; 3.4449x over previous
//
#include <hip/hip_runtime.h>
#include <stdint.h>

typedef unsigned long long u64;
typedef unsigned int u32;
typedef u32 v8u __attribute__((ext_vector_type(8)));

#define K_MSG   1024
#define N_CODE  2048
#define NB      32768
#define KW      16        // 1024 bits / 64 = 16 u64 words per row/col
#define ROWS_TILE 256
#define COLS_TILE 64

// ---------------- pack b: [NB][K_MSG] int32 -> [NB][KW] u64 ----------------
__global__ void pack_b_kernel(const int* __restrict__ b, u64* __restrict__ bp,
                              int nwords) {
    const int lane  = threadIdx.x & 63;
    const int wave  = blockIdx.x * (blockDim.x >> 6) + (threadIdx.x >> 6);
    const int nwave = gridDim.x * (blockDim.x >> 6);
    for (int word = wave; word < nwords; word += nwave) {
        int v = b[(size_t)word * 64 + lane];
        u64 m = __ballot((v & 1) != 0);
        if (lane == 0) bp[word] = m;
    }
}

// ---------------- pack G: Gp[w][j], bit t = G[w*64+t][j] --------------------
__global__ void pack_g_kernel(const int* __restrict__ G, u64* __restrict__ gp) {
    const int lane = threadIdx.x & 63;
    const int wave = blockIdx.x * (blockDim.x >> 6) + (threadIdx.x >> 6); // 0..511
    const int w    = wave >> 5;   // 0..15
    const int jb   = wave & 31;   // 0..31
    const int j    = jb * 64 + lane;
    u64 word = 0;
#pragma unroll 16
    for (int t = 0; t < 64; ++t) {
        int v = G[(size_t)(w * 64 + t) * N_CODE + j];
        word |= (u64)(v & 1) << t;
    }
    gp[(size_t)w * N_CODE + j] = word;
}

// ---------------- main ------------------------------------------------------
// Block 256 thr = 4 waves; lane = column (64 cols/block), wave ty does rows
// r0+ty, +4, ... (64 iters). Rows are wave-uniform -> fetched into SGPRs via
// s_load_dwordx8 (scalar pipe), ping-pong prefetch. g column words in VGPRs.
// v_and_b32 takes one SGPR operand, so the AND/XOR tree is pure VALU with no
// per-row address math.

struct RowRegs { v8u a, b, c, d; };   // 32 SGPRs = one 128B packed row

// 4 outputs written inside one asm block while input %4 still live -> early-clobber.
#define SLOAD_ROW(dst, addr)                                            \
    asm volatile("s_load_dwordx8 %0, %4, 0x0\n\t"                       \
                 "s_load_dwordx8 %1, %4, 0x20\n\t"                      \
                 "s_load_dwordx8 %2, %4, 0x40\n\t"                      \
                 "s_load_dwordx8 %3, %4, 0x60"                          \
                 : "=&s"(dst.a), "=&s"(dst.b), "=&s"(dst.c), "=&s"(dst.d) \
                 : "s"(addr))

// rule #18: sched_barrier(0) right after the inline-asm lgkmcnt wait so the
// compiler can't hoist register-only consumers above it.
#define SWAIT() do { asm volatile("s_waitcnt lgkmcnt(0)" ::: "memory");  \
                     __builtin_amdgcn_sched_barrier(0); } while (0)

#define COMPUTE_STORE(cur, s_) do {                                     \
    u32 a0 = 0, a1 = 0, a2 = 0, a3 = 0;                                 \
    _Pragma("unroll")                                                   \
    for (int i = 0; i < 8; ++i) {                                       \
        a0 ^= cur.a[i] & gl[i];                                         \
        a1 ^= cur.b[i] & gl[8 + i];                                     \
        a2 ^= cur.c[i] & gl[16 + i];                                    \
        a3 ^= cur.d[i] & gl[24 + i];                                    \
    }                                                                   \
    u32 acc = (a0 ^ a1) ^ (a2 ^ a3);                                    \
    op[(size_t)(s_) * 4 * N_CODE] = (int)(__popc(acc) & 1);             \
} while (0)

__global__ __launch_bounds__(256) void encode_main(const u64* __restrict__ bp,
                                                   const u64* __restrict__ gp,
                                                   int* __restrict__ out) {
    const int lane = threadIdx.x & 63;
    const int ty   = threadIdx.x >> 6;
    const int j    = blockIdx.x * COLS_TILE + lane;
    const int r0   = blockIdx.y * ROWS_TILE;

    // g column words -> 32 u32 in VGPRs (unroll-constant indexing only)
    u32 gl[32];
#pragma unroll
    for (int w = 0; w < KW; ++w) {
        u64 v = gp[(size_t)w * N_CODE + j];
        gl[2 * w]     = (u32)v;
        gl[2 * w + 1] = (u32)(v >> 32);
    }

    // uniform row base for the scalar loads
    const int row_u = __builtin_amdgcn_readfirstlane(r0 + ty);
    const u64* rp = bp + ((size_t)row_u << 4);     // +64 u64 per iteration (4 rows)
    int* __restrict__ op = out + (size_t)(r0 + ty) * N_CODE + j;

    RowRegs A, B;
    SLOAD_ROW(A, rp);
    SWAIT();

#pragma unroll 1
    for (int s = 0; s < 62; s += 2) {
        SLOAD_ROW(B, rp + (size_t)(s + 1) * 64);   // prefetch row s+1
        COMPUTE_STORE(A, s);                       // hides B latency
        SWAIT();
        SLOAD_ROW(A, rp + (size_t)(s + 2) * 64);   // prefetch row s+2
        COMPUTE_STORE(B, s + 1);                   // hides A latency
        SWAIT();
    }
    SLOAD_ROW(B, rp + (size_t)63 * 64);
    COMPUTE_STORE(A, 62);
    SWAIT();
    COMPUTE_STORE(B, 63);
}

// ---------------- fallback (only if ws too small) ---------------------------
__global__ void encode_naive(const int* __restrict__ b, const int* __restrict__ G,
                             int* __restrict__ out) {
    size_t idx = (size_t)blockIdx.x * blockDim.x + threadIdx.x;
    size_t total = (size_t)NB * N_CODE;
    if (idx >= total) return;
    int i = (int)(idx / N_CODE);
    int j = (int)(idx % N_CODE);
    int acc = 0;
    for (int k = 0; k < K_MSG; ++k)
        acc ^= b[(size_t)i * K_MSG + k] & G[(size_t)k * N_CODE + j];
    out[idx] = acc & 1;
}

extern "C" void kernel_launch(void* const* d_in, const int* in_sizes, int n_in,
                              void* d_out, int out_size, void* d_ws, size_t ws_size,
                              hipStream_t stream) {
    const int* b = (const int*)d_in[0];
    const int* G = (const int*)d_in[1];
    int* out = (int*)d_out;

    const size_t bp_bytes = (size_t)NB * KW * sizeof(u64);      // 4 MiB
    const size_t gp_bytes = (size_t)N_CODE * KW * sizeof(u64);  // 256 KiB

    if (ws_size < bp_bytes + gp_bytes) {
        size_t total = (size_t)NB * N_CODE;
        encode_naive<<<(unsigned)((total + 255) / 256), 256, 0, stream>>>(b, G, out);
        return;
    }

    u64* bp = (u64*)d_ws;
    u64* gp = (u64*)((char*)d_ws + bp_bytes);

    pack_b_kernel<<<2048, 256, 0, stream>>>(b, bp, NB * KW);
    pack_g_kernel<<<128, 256, 0, stream>>>(G, gp);

    dim3 grid(N_CODE / COLS_TILE, NB / ROWS_TILE);  // 32 x 128
    encode_main<<<grid, 256, 0, stream>>>(bp, gp, out);
}

// Round 4
// 154.537 us; speedup vs baseline: 3.5120x; 1.0195x over previous
//
#include <hip/hip_runtime.h>
#include <stdint.h>

typedef unsigned long long u64;
typedef unsigned int u32;
typedef u32 v8u __attribute__((ext_vector_type(8)));
typedef u32 v4u __attribute__((ext_vector_type(4)));
typedef int v2i __attribute__((ext_vector_type(2)));

#define K_MSG   1024
#define N_CODE  2048
#define NB      32768
#define KW      16        // 1024 bits / 64 = 16 u64 words per row/col
#define ROWS_TILE 256
#define COLS_TILE 128     // 2 columns per lane

// ---------------- pack b: [NB][K_MSG] int32 -> [NB][KW] u64 ----------------
__global__ void pack_b_kernel(const int* __restrict__ b, u64* __restrict__ bp,
                              int nwords) {
    const int lane  = threadIdx.x & 63;
    const int wave  = blockIdx.x * (blockDim.x >> 6) + (threadIdx.x >> 6);
    const int nwave = gridDim.x * (blockDim.x >> 6);
    for (int word = wave; word < nwords; word += nwave) {
        int v = b[(size_t)word * 64 + lane];
        u64 m = __ballot((v & 1) != 0);
        if (lane == 0) bp[word] = m;
    }
}

// ---------------- pack G: Gp[w][j], bit t = G[w*64+t][j] --------------------
__global__ void pack_g_kernel(const int* __restrict__ G, u64* __restrict__ gp) {
    const int lane = threadIdx.x & 63;
    const int wave = blockIdx.x * (blockDim.x >> 6) + (threadIdx.x >> 6); // 0..511
    const int w    = wave >> 5;   // 0..15
    const int jb   = wave & 31;   // 0..31
    const int j    = jb * 64 + lane;
    u64 word = 0;
#pragma unroll 16
    for (int t = 0; t < 64; ++t) {
        int v = G[(size_t)(w * 64 + t) * N_CODE + j];
        word |= (u64)(v & 1) << t;
    }
    gp[(size_t)w * N_CODE + j] = word;
}

// ---------------- main ------------------------------------------------------
// Block 256 thr = 4 waves; lane owns columns j0,j0+1 (128 cols/block), wave ty
// does rows r0+ty, +4, ... (64 iters). Rows are wave-uniform -> SGPRs via
// s_load_dwordx8 ping-pong; both column XOR-trees share the SGPR row operand.

struct RowRegs { v8u a, b, c, d; };   // 32 SGPRs = one 128B packed row

#define SLOAD_ROW(dst, addr)                                            \
    asm volatile("s_load_dwordx8 %0, %4, 0x0\n\t"                       \
                 "s_load_dwordx8 %1, %4, 0x20\n\t"                      \
                 "s_load_dwordx8 %2, %4, 0x40\n\t"                      \
                 "s_load_dwordx8 %3, %4, 0x60"                          \
                 : "=&s"(dst.a), "=&s"(dst.b), "=&s"(dst.c), "=&s"(dst.d) \
                 : "s"(addr))

// rule #18: sched_barrier(0) right after the inline-asm wait so register-only
// consumers of the loaded SGPRs can't be hoisted above it.
#define SWAIT() do { asm volatile("s_waitcnt lgkmcnt(0)" ::: "memory");  \
                     __builtin_amdgcn_sched_barrier(0); } while (0)

#define COMPUTE_STORE(cur, s_) do {                                     \
    u32 x0 = 0, x1 = 0, x2 = 0, x3 = 0;                                 \
    u32 y0 = 0, y1 = 0, y2 = 0, y3 = 0;                                 \
    _Pragma("unroll")                                                   \
    for (int i = 0; i < 8; ++i) {                                       \
        x0 ^= cur.a[i] & g0l[i];      y0 ^= cur.a[i] & g1l[i];          \
        x1 ^= cur.b[i] & g0l[8 + i];  y1 ^= cur.b[i] & g1l[8 + i];      \
        x2 ^= cur.c[i] & g0l[16 + i]; y2 ^= cur.c[i] & g1l[16 + i];     \
        x3 ^= cur.d[i] & g0l[24 + i]; y3 ^= cur.d[i] & g1l[24 + i];     \
    }                                                                   \
    u32 ax = (x0 ^ x1) ^ (x2 ^ x3);                                     \
    u32 ay = (y0 ^ y1) ^ (y2 ^ y3);                                     \
    v2i r; r.x = (int)(__popc(ax) & 1); r.y = (int)(__popc(ay) & 1);    \
    *(v2i*)(op + (size_t)(s_) * 4 * N_CODE) = r;                        \
} while (0)

__global__ __launch_bounds__(256, 4) void encode_main(const u64* __restrict__ bp,
                                                      const u64* __restrict__ gp,
                                                      int* __restrict__ out) {
    const int lane = threadIdx.x & 63;
    const int ty   = threadIdx.x >> 6;
    const int j0   = blockIdx.x * COLS_TILE + lane * 2;
    const int r0   = blockIdx.y * ROWS_TILE;

    // two adjacent columns' packed words: contiguous u64 pair -> dwordx4 loads
    u32 g0l[32], g1l[32];
#pragma unroll
    for (int w = 0; w < KW; ++w) {
        v4u v = *(const v4u*)(gp + (size_t)w * N_CODE + j0);
        g0l[2 * w]     = v.x;
        g0l[2 * w + 1] = v.y;
        g1l[2 * w]     = v.z;
        g1l[2 * w + 1] = v.w;
    }

    const int row_u = __builtin_amdgcn_readfirstlane(r0 + ty);
    const u64* rp = bp + ((size_t)row_u << 4);     // +64 u64 per iteration (4 rows)
    int* __restrict__ op = out + (size_t)(r0 + ty) * N_CODE + j0;

    RowRegs A, B;
    SLOAD_ROW(A, rp);
    SWAIT();

#pragma unroll 1
    for (int s = 0; s < 62; s += 2) {
        SLOAD_ROW(B, rp + (size_t)(s + 1) * 64);   // prefetch row s+1
        COMPUTE_STORE(A, s);                       // ~290 cyc hides the latency
        SWAIT();
        SLOAD_ROW(A, rp + (size_t)(s + 2) * 64);   // prefetch row s+2
        COMPUTE_STORE(B, s + 1);
        SWAIT();
    }
    SLOAD_ROW(B, rp + (size_t)63 * 64);
    COMPUTE_STORE(A, 62);
    SWAIT();
    COMPUTE_STORE(B, 63);
}

// ---------------- fallback (only if ws too small) ---------------------------
__global__ void encode_naive(const int* __restrict__ b, const int* __restrict__ G,
                             int* __restrict__ out) {
    size_t idx = (size_t)blockIdx.x * blockDim.x + threadIdx.x;
    size_t total = (size_t)NB * N_CODE;
    if (idx >= total) return;
    int i = (int)(idx / N_CODE);
    int j = (int)(idx % N_CODE);
    int acc = 0;
    for (int k = 0; k < K_MSG; ++k)
        acc ^= b[(size_t)i * K_MSG + k] & G[(size_t)k * N_CODE + j];
    out[idx] = acc & 1;
}

extern "C" void kernel_launch(void* const* d_in, const int* in_sizes, int n_in,
                              void* d_out, int out_size, void* d_ws, size_t ws_size,
                              hipStream_t stream) {
    const int* b = (const int*)d_in[0];
    const int* G = (const int*)d_in[1];
    int* out = (int*)d_out;

    const size_t bp_bytes = (size_t)NB * KW * sizeof(u64);      // 4 MiB
    const size_t gp_bytes = (size_t)N_CODE * KW * sizeof(u64);  // 256 KiB

    if (ws_size < bp_bytes + gp_bytes) {
        size_t total = (size_t)NB * N_CODE;
        encode_naive<<<(unsigned)((total + 255) / 256), 256, 0, stream>>>(b, G, out);
        return;
    }

    u64* bp = (u64*)d_ws;
    u64* gp = (u64*)((char*)d_ws + bp_bytes);

    pack_b_kernel<<<2048, 256, 0, stream>>>(b, bp, NB * KW);
    pack_g_kernel<<<128, 256, 0, stream>>>(G, gp);

    dim3 grid(N_CODE / COLS_TILE, NB / ROWS_TILE);  // 16 x 128
    encode_main<<<grid, 256, 0, stream>>>(bp, gp, out);
}